// Round 1
// baseline (268.946 us; speedup 1.0000x reference)
//
#include <hip/hip_runtime.h>

// DAGConstraintLayer: out[b,i] = sigmoid(min over root-to-i ancestor chain of x[b,a]).
// sigmoid is monotone => min of sigmoids == sigmoid of min; collapses the whole
// level-sweep into an independent per-element ancestor-chain min. Memory-bound:
// 266 MB total traffic -> ~42 us roofline at 6.3 TB/s.

#define NODES 127u

__global__ __launch_bounds__(256) void DAGConstraintLayer_kernel(
        const float* __restrict__ x, float* __restrict__ out, unsigned total) {
    unsigned e = blockIdx.x * 256u + threadIdx.x;
    if (e >= total) return;

    unsigned b = e / NODES;              // compiler emits magic-multiply
    unsigned i = e - b * NODES;
    const float* __restrict__ row = x + (size_t)b * NODES;

    float v = row[i];                    // coalesced: consecutive lanes, consecutive addrs
    unsigned j = i;
    // Branchless walk up the tree; depth <= 6 for 127 nodes. Once j hits the
    // root, further iterations re-min with row[0] (idempotent, L1-broadcast).
    #pragma unroll
    for (int d = 0; d < 6; ++d) {
        j = j ? (j - 1u) >> 1 : 0u;
        v = fminf(v, row[j]);            // ancestor reads: same 508-B row, L1-hot
    }

    // fast sigmoid: 1/(1+exp(-v)); __expf -> v_exp_f32 path
    out[e] = 1.0f / (1.0f + __expf(-v));
}

extern "C" void kernel_launch(void* const* d_in, const int* in_sizes, int n_in,
                              void* d_out, int out_size, void* d_ws, size_t ws_size,
                              hipStream_t stream) {
    const float* x = (const float*)d_in[0];
    float* out = (float*)d_out;
    unsigned total = (unsigned)in_sizes[0];          // 262144 * 127 = 33,292,288
    unsigned grid = (total + 255u) / 256u;           // 130,048 exactly
    DAGConstraintLayer_kernel<<<grid, 256, 0, stream>>>(x, out, total);
}

// Round 2
// 241.023 us; speedup vs baseline: 1.1159x; 1.1159x over previous
//
#include <hip/hip_runtime.h>

// DAGConstraintLayer: out[b,i] = sigmoid(min over root-to-i ancestor chain of x[b,i]).
// sigmoid monotone => sigmoid(min(chain)). One wave per row (127 nodes): lane l holds
// nodes {2l, 2l+1} from ONE coalesced float2 load; ancestor-path min computed in
// registers via 3 rounds of shuffle doubling (jump 1,2,4 covers depth<=6); one
// coalesced float2 store. VMEM lane-ops drop from 8/elem to ~1.1/elem — the R1
// kernel was address-throughput bound (8 addrs/elem ~= 108us at 4 addr/cyc/CU).

#define NODES 127
#define BLOCK 256
#define GRID  2048   // 2048 blocks * 4 waves = 8192 waves; 262144 rows / 8192 = 32 rows/wave exactly

typedef float f2 __attribute__((ext_vector_type(2), aligned(4)));  // rows are 4B-aligned only (508 B stride)

__global__ __launch_bounds__(BLOCK) void dag_kernel(const float* __restrict__ x,
                                                    float* __restrict__ out,
                                                    int rows) {
    const int lane  = threadIdx.x & 63;
    const int wave  = blockIdx.x * (BLOCK / 64) + (threadIdx.x >> 6);
    const int nwave = GRID * (BLOCK / 64);

    // Nodes held by this lane: n0 = 2*lane, n1 = 2*lane+1 (n1 is a pad slot for lane 63).
    const int n0 = 2 * lane, n1 = 2 * lane + 1;

    // Precompute shuffle sources once (pure function of lane). Ancestor at distance
    // d of node n: ((n+1)>>d)-1, clamped to root. Node m lives at lane m>>1, comp m&1.
    // No anc index ever equals 127, so the pad slot never feeds a stored value.
    int sl[3][2], cm[3][2];
    #pragma unroll
    for (int r = 0; r < 3; ++r) {
        const int d = 1 << r;
        int t0 = (n0 + 1) >> d; int a0 = t0 ? t0 - 1 : 0;
        int t1 = (n1 + 1) >> d; int a1 = t1 ? t1 - 1 : 0;
        sl[r][0] = a0 >> 1; cm[r][0] = a0 & 1;
        sl[r][1] = a1 >> 1; cm[r][1] = a1 & 1;
    }

    for (int r = wave; r < rows; r += nwave) {
        const float* row = x + (size_t)r * NODES;
        float vx, vy;
        if (lane < 63) {                      // coalesced: 8 B/lane, 504 B contiguous
            f2 t = *(const f2*)(row + n0);
            vx = t.x; vy = t.y;
        } else {                              // node 126 only; pad slot = +inf
            vx = row[126];
            vy = __builtin_inff();
        }

        // Hillis-Steele on the ancestor path: after rounds d=1,2,4 each node's value
        // is min over ancestors at distance <= 7 (>= tree depth 6).
        #pragma unroll
        for (int rd = 0; rd < 3; ++rd) {
            float ax = vx, ay = vy;           // snapshot: all lanes shuffle pre-round values
            float g0x = __shfl(ax, sl[rd][0]);
            float g0y = __shfl(ay, sl[rd][0]);
            float g1x = __shfl(ax, sl[rd][1]);
            float g1y = __shfl(ay, sl[rd][1]);
            float p0 = cm[rd][0] ? g0y : g0x;
            float p1 = cm[rd][1] ? g1y : g1x;
            vx = fminf(vx, p0);
            vy = fminf(vy, p1);
        }

        float sx = 1.0f / (1.0f + __expf(-vx));
        float sy = 1.0f / (1.0f + __expf(-vy));

        float* orow = out + (size_t)r * NODES;
        if (lane < 63) {
            f2 t; t.x = sx; t.y = sy;
            *(f2*)(orow + n0) = t;
        } else {
            orow[126] = sx;
        }
    }
}

extern "C" void kernel_launch(void* const* d_in, const int* in_sizes, int n_in,
                              void* d_out, int out_size, void* d_ws, size_t ws_size,
                              hipStream_t stream) {
    const float* x = (const float*)d_in[0];
    float* out = (float*)d_out;
    int rows = in_sizes[0] / NODES;           // 262144
    dag_kernel<<<GRID, BLOCK, 0, stream>>>(x, out, rows);
}

// Round 3
// 230.061 us; speedup vs baseline: 1.1690x; 1.0476x over previous
//
#include <hip/hip_runtime.h>

// DAGConstraintLayer: out[b,i] = sigmoid(min over root-to-i chain of x[b,i]).
// R2 was limited by misaligned float2 VMEM (508-B row stride -> split dword ops)
// and 12 ds_bpermute/row on the LDS pipe (~30us/CU). R3: stage 32 rows (16256 B,
// = 1016 float4, 16B-aligned) through LDS with coalesced float4 in/out; compute
// with 8 threads/row, each doing a register-resident DFS over its depth-3
// subtree (path-min in regs, 1 ds_read + 1 ds_write per node, in-place).
// 16.25 KB LDS -> 8 blocks/CU -> 32 waves/CU.

#define NODES 127
#define RPB   32                 // rows per block
#define BLOCK 256
#define TILE_F4 (RPB * NODES / 4)   // 1016

__device__ __forceinline__ float sigf(float v) {
    return 1.0f / (1.0f + __expf(-v));
}

// Unrolled preorder DFS over subtree rooted at node n (runtime), D levels.
// pm = min over all ancestors of n (strict). Writes sigmoid(pathmin) in place.
template<int D>
__device__ __forceinline__ void visit(float* __restrict__ buf, int o, int n, float pm) {
    float v = fminf(pm, buf[o + n]);
    buf[o + n] = sigf(v);
    if constexpr (D > 1) {
        visit<D - 1>(buf, o, 2 * n + 1, v);
        visit<D - 1>(buf, o, 2 * n + 2, v);
    }
}

__global__ __launch_bounds__(BLOCK, 8) void dag_kernel(const float* __restrict__ x,
                                                       float* __restrict__ out) {
    __shared__ float buf[RPB * NODES];          // 16,256 B

    const size_t base = (size_t)blockIdx.x * (RPB * NODES);

    // ---- stage-in: coalesced float4 (base is 16B-aligned: 32*127*4 = 16256) ----
    const float4* __restrict__ src = (const float4*)(x + base);
    float4* __restrict__ b4 = (float4*)buf;
    int t = threadIdx.x;
    #pragma unroll
    for (int k = 0; k < 3; ++k) b4[t + k * BLOCK] = src[t + k * BLOCK];
    if (t + 3 * BLOCK < TILE_F4) b4[t + 3 * BLOCK] = src[t + 3 * BLOCK];
    __syncthreads();

    // ---- compute: 8 threads per row, one depth-3 subtree each ----
    const int rl = t >> 3;                       // local row 0..31
    const int s  = t & 7;                        // subtree id 0..7
    const int o  = rl * NODES;
    const int m3 = 7 + s;                        // subtree root (depth 3)
    const int m2 = (m3 - 1) >> 1;                // depth-2 ancestor
    const int m1 = (m2 - 1) >> 1;                // depth-1 ancestor

    // Raw ancestor reads BEFORE any top-node writes (same wave: all 8 subtree
    // threads of a row are in one wave; LDS ops issue in program order).
    float x0 = buf[o];
    float a1 = buf[o + m1];
    float a2 = buf[o + m2];

    if (s == 0) {                                // nodes 0..6 (depths 0-2)
        float X2 = buf[o + 2], X4 = buf[o + 4];
        float X5 = buf[o + 5], X6 = buf[o + 6];
        // for s==0: m1==1, m2==3 -> a1 = x[1], a2 = x[3]
        float p1 = fminf(x0, a1);
        float p2 = fminf(x0, X2);
        buf[o + 0] = sigf(x0);
        buf[o + 1] = sigf(p1);
        buf[o + 2] = sigf(p2);
        buf[o + 3] = sigf(fminf(p1, a2));
        buf[o + 4] = sigf(fminf(p1, X4));
        buf[o + 5] = sigf(fminf(p2, X5));
        buf[o + 6] = sigf(fminf(p2, X6));
    }

    float pm = fminf(fminf(x0, a1), a2);         // v_min3
    visit<4>(buf, o, m3, pm);                    // 15 nodes, depths 3..6
    __syncthreads();

    // ---- stage-out: coalesced float4 ----
    float4* __restrict__ dst = (float4*)(out + base);
    #pragma unroll
    for (int k = 0; k < 3; ++k) dst[t + k * BLOCK] = b4[t + k * BLOCK];
    if (t + 3 * BLOCK < TILE_F4) dst[t + 3 * BLOCK] = b4[t + 3 * BLOCK];
}

extern "C" void kernel_launch(void* const* d_in, const int* in_sizes, int n_in,
                              void* d_out, int out_size, void* d_ws, size_t ws_size,
                              hipStream_t stream) {
    const float* x = (const float*)d_in[0];
    float* out = (float*)d_out;
    int rows = in_sizes[0] / NODES;              // 262144
    int grid = rows / RPB;                       // 8192 exactly
    dag_kernel<<<grid, BLOCK, 0, stream>>>(x, out);
}